// Round 11
// baseline (356.434 us; speedup 1.0000x reference)
//
#include <hip/hip_runtime.h>

#define N_NODES 100000
#define N_GRAPHS 64
#define N_EDGES 600000
#define BN_EPS 1e-5f

// XCD-binned fill: fill blocks sit at blockIdx=(fb/3)*5+fb%3; per 24 fill
// blocks (40 blockIdx, 40%8==0) each blockIdx%8 residue appears exactly 3x.
// Static tables map l=fb%24 -> (xcd=blockIdx&7, rank 0..2); sub=(fb/24)*3+rank.
// Each group covers subs 0..292 exactly once; 293 chunks of 2048 cover all
// edges. Correct for ANY actual placement (partition is by dst value).
#define FILL_NSUB 293
#define FILL_PER  2048
__device__ __constant__ const signed char XCD_OF_L[24] =
    {0,1,2,5,6,7,2,3,4,7,0,1,4,5,6,1,2,3,6,7,0,3,4,5};
__device__ __constant__ const signed char RANK_OF_L[24] =
    {0,0,0,0,0,0,1,0,0,1,1,1,1,1,1,2,2,1,2,2,2,2,2,2};

typedef unsigned short bf16_t;

__device__ __forceinline__ unsigned short f2bf(float f) {
    unsigned int u = __float_as_uint(f);
    u += 0x7FFF + ((u >> 16) & 1);
    return (unsigned short)(u >> 16);
}
__device__ __forceinline__ uint2 pack4(float a, float b, float c, float d) {
    uint2 p;
    p.x = (unsigned)f2bf(a) | ((unsigned)f2bf(b) << 16);
    p.y = (unsigned)f2bf(c) | ((unsigned)f2bf(d) << 16);
    return p;
}
// accumulate 8 bf16 (uint4) into acc[0..7]
__device__ __forceinline__ void bf8_acc(uint4 q, float* acc) {
    acc[0] += __uint_as_float(q.x << 16);
    acc[1] += __uint_as_float(q.x & 0xFFFF0000u);
    acc[2] += __uint_as_float(q.y << 16);
    acc[3] += __uint_as_float(q.y & 0xFFFF0000u);
    acc[4] += __uint_as_float(q.z << 16);
    acc[5] += __uint_as_float(q.z & 0xFFFF0000u);
    acc[6] += __uint_as_float(q.w << 16);
    acc[7] += __uint_as_float(q.w & 0xFFFF0000u);
}

// Gather one 64-node tile into LDS (stride SS), bias+ReLU applied.
// R3-proven form: 512-thread single pass, 8 lanes/node, unroll-4 + tail.
template <int SS>
__device__ __forceinline__ void gather_tile_to_lds512(
    const bf16_t* __restrict__ y, const int* __restrict__ rowptr,
    const int* __restrict__ eids, const float* __restrict__ b1,
    float* sT, long base, int n_nodes, int tid) {
    const uint4* yv = (const uint4*)y;
    const int f = tid & 7;
    const int lr = tid >> 3;   // local row 0..63
    float4 b0 = ((const float4*)b1)[f * 2];
    float4 b1v = ((const float4*)b1)[f * 2 + 1];
    long node = base + lr;
    float* sp = &sT[lr * SS + f * 8];
    if (node < n_nodes) {
        float acc[8] = {};
        bf8_acc(yv[node * 8 + f], acc);
        int bgn = rowptr[node], end = rowptr[node + 1];
        int i = bgn;
        for (; i + 3 < end; i += 4) {
            int s0 = eids[i], s1 = eids[i + 1], s2 = eids[i + 2], s3 = eids[i + 3];
            uint4 q0 = yv[(long)s0 * 8 + f];
            uint4 q1 = yv[(long)s1 * 8 + f];
            uint4 q2 = yv[(long)s2 * 8 + f];
            uint4 q3 = yv[(long)s3 * 8 + f];
            bf8_acc(q0, acc); bf8_acc(q1, acc); bf8_acc(q2, acc); bf8_acc(q3, acc);
        }
        for (; i < end; ++i) bf8_acc(yv[(long)eids[i] * 8 + f], acc);
        float4 o0, o1;
        o0.x = fmaxf(acc[0] + b0.x, 0.0f);
        o0.y = fmaxf(acc[1] + b0.y, 0.0f);
        o0.z = fmaxf(acc[2] + b0.z, 0.0f);
        o0.w = fmaxf(acc[3] + b0.w, 0.0f);
        o1.x = fmaxf(acc[4] + b1v.x, 0.0f);
        o1.y = fmaxf(acc[5] + b1v.y, 0.0f);
        o1.z = fmaxf(acc[6] + b1v.z, 0.0f);
        o1.w = fmaxf(acc[7] + b1v.w, 0.0f);
        *(float4*)sp = o0;
        *(float4*)(sp + 4) = o1;
    } else {
        float4 z = {0.0f, 0.0f, 0.0f, 0.0f};
        *(float4*)sp = z;
        *(float4*)(sp + 4) = z;
    }
}

// ===========================================================================
// CSR build
// ===========================================================================
__global__ void deg_hist_kernel(const int* __restrict__ dst,
                                int* __restrict__ deg, int n_edges) {
    int e = blockIdx.x * blockDim.x + threadIdx.x;
    if (e < n_edges) atomicAdd(&deg[dst[e]], 1);
}

// One-kernel exclusive scan: per-block scan + aggregate publish (atomicExch
// into -1-initialized slot) + parallel spin-read of predecessors (atomicAdd,
// device-scope => cross-XCD safe). All 98 blocks co-resident.
__global__ __launch_bounds__(1024)
void scan_fused_kernel(const int* __restrict__ deg, int* __restrict__ rowptr,
                       int* __restrict__ agg, int n, int total) {
    __shared__ int s[1024];
    __shared__ int s2[128];
    __shared__ int offset_sh;
    const int b = blockIdx.x;
    const int i = b * 1024 + threadIdx.x;
    int v = (i < n) ? deg[i] : 0;
    s[threadIdx.x] = v;
    __syncthreads();
    for (int off = 1; off < 1024; off <<= 1) {
        int t = (threadIdx.x >= (unsigned)off) ? s[threadIdx.x - off] : 0;
        __syncthreads();
        s[threadIdx.x] += t;
        __syncthreads();
    }
    // publish this block's total (slot pre-initialized to -1 by prep)
    if (threadIdx.x == 1023) atomicExch(&agg[b], s[1023]);
    // threads 0..b-1 spin-read predecessor aggregates
    if (threadIdx.x < b) {
        int val;
        do { val = atomicAdd(&agg[threadIdx.x], 0); } while (val == -1);
        s2[threadIdx.x] = val;
    }
    __syncthreads();
    if (threadIdx.x == 0) {
        int off = 0;
        for (int k = 0; k < b; ++k) off += s2[k];
        offset_sh = off;
    }
    __syncthreads();
    const int off = offset_sh;
    if (i < n) rowptr[i] = off + s[threadIdx.x] - v;
    else if (i == n) rowptr[n] = total;
}

// ===========================================================================
// MERGED fill_bounds + pre_gemm (256 threads, 3:2). Fill role XCD-binned
// with CORRECT blockIdx&7 alignment (R10's fb&7 was scrambled vs placement).
// ===========================================================================
__global__ __launch_bounds__(256)
void fill_pre_kernel(const int* __restrict__ src, const int* __restrict__ dst,
                     const int* __restrict__ rowptr, int* __restrict__ cursor,
                     int* __restrict__ eids, const int* __restrict__ batch,
                     int* __restrict__ gstart,
                     const float* __restrict__ x, const float* __restrict__ w1T,
                     bf16_t* __restrict__ y, int n_edges, int n_nodes) {
    __shared__ float w1s[64 * 128];
    const int bq = blockIdx.x / 5, br = blockIdx.x % 5;

    if (br < 3) {
        // ------------------- fill role (3 of every 5 blocks) -------------------
        const int fb = bq * 3 + br;            // flat fill-block id, 0..2345
        // graph bounds (original flat mapping over nodes)
        int e0 = fb * 256 + threadIdx.x;
        if (e0 < n_nodes) {
            if (e0 == 0) {
                for (int g = 0; g <= batch[0]; ++g) gstart[g] = 0;
            } else {
                int b0 = batch[e0 - 1], b1 = batch[e0];
                for (int g = b0 + 1; g <= b1; ++g) gstart[g] = e0;
            }
            if (e0 == n_nodes - 1) {
                for (int g = batch[e0] + 1; g <= N_GRAPHS; ++g) gstart[g] = n_nodes;
            }
        }
        // XCD-binned eids fill: label by actual blockIdx&7 (= placement
        // heuristic), static rank table gives each group subs 0..292 once.
        const int w = fb / 24, l = fb % 24;
        const int xcd = XCD_OF_L[l];
        const int sub = w * 3 + RANK_OF_L[l];
        if (sub < FILL_NSUB) {
            const int lo = xcd * (N_NODES / 8);
            const int hi = lo + (N_NODES / 8);
            int beg = sub * FILL_PER;
            int end = beg + FILL_PER;
            if (end > n_edges) end = n_edges;
            for (int e = beg + threadIdx.x; e < end; e += 256) {
                int t = dst[e];
                if (t >= lo && t < hi) {
                    int pos = rowptr[t] + atomicAdd(&cursor[t], 1);
                    eids[pos] = src[e];
                }
            }
        }
        return;
    }

    // ------------------- gemm role (2 of every 5 blocks) -------------------
    const int gb = bq * 2 + (br - 3);
    const long base = (long)gb * 64;
    if (base >= n_nodes) return;
    const int tid = threadIdx.x;

    const float4* gw1 = (const float4*)w1T;
    for (int i4 = tid; i4 < 16 * 128; i4 += 256) {
        int row = i4 >> 5, k4 = i4 & 31;
        *(float4*)&w1s[row * 128 + ((k4 ^ ((row >> 2) & 7)) << 2)] = gw1[i4];
    }
    __syncthreads();

    const int jg = tid & 15, ng = tid >> 4, xw = jg & 7;
    const float* wp = &w1s[(jg * 4) * 128];
    const float4* xv = (const float4*)x;
    long r[4];
    #pragma unroll
    for (int i = 0; i < 4; ++i) {
        long rr = base + ng * 4 + i;
        r[i] = (rr < n_nodes) ? rr : (n_nodes - 1);  // clamp: x has no padding
    }
    float acc[4][4] = {};
    #pragma unroll 4
    for (int k4 = 0; k4 < 32; ++k4) {
        const int ko = (k4 ^ xw) << 2;
        float4 w0 = *(const float4*)&wp[0 * 128 + ko];
        float4 w1v = *(const float4*)&wp[1 * 128 + ko];
        float4 w2v = *(const float4*)&wp[2 * 128 + ko];
        float4 w3v = *(const float4*)&wp[3 * 128 + ko];
        #pragma unroll
        for (int i = 0; i < 4; ++i) {
            float4 a = xv[r[i] * 32 + k4];
            acc[i][0] = fmaf(a.x, w0.x, fmaf(a.y, w0.y, fmaf(a.z, w0.z, fmaf(a.w, w0.w, acc[i][0]))));
            acc[i][1] = fmaf(a.x, w1v.x, fmaf(a.y, w1v.y, fmaf(a.z, w1v.z, fmaf(a.w, w1v.w, acc[i][1]))));
            acc[i][2] = fmaf(a.x, w2v.x, fmaf(a.y, w2v.y, fmaf(a.z, w2v.z, fmaf(a.w, w2v.w, acc[i][2]))));
            acc[i][3] = fmaf(a.x, w3v.x, fmaf(a.y, w3v.y, fmaf(a.z, w3v.z, fmaf(a.w, w3v.w, acc[i][3]))));
        }
    }
    #pragma unroll
    for (int i = 0; i < 4; ++i) {
        long n = base + ng * 4 + i;
        if (n < n_nodes) {
            *(uint2*)(y + n * 64 + jg * 4) = pack4(acc[i][0], acc[i][1], acc[i][2], acc[i][3]);
        }
    }
}

// ===========================================================================
// Prep (blockIdx.y = layer); y==0 blocks also zero deg/cursor/d_out and
// init scan aggregates to -1.
// ===========================================================================
struct LayerPrep {
    const float *w1, *w2, *b2, *g, *bb, *m, *v;
    float *w1T, *w2sT, *bias2;
    int DIN, DOUT;
};
struct PrepAll { LayerPrep l[3]; };

__global__ void prep_all_kernel(PrepAll pa, int* __restrict__ deg,
                                int* __restrict__ cursor, float* __restrict__ out_zero,
                                int* __restrict__ agg) {
    LayerPrep P = pa.l[blockIdx.y];
    int i = blockIdx.x * blockDim.x + threadIdx.x;
    if (blockIdx.y == 0) {
        int stride = gridDim.x * blockDim.x;
        for (int k = i; k < N_NODES; k += stride) { deg[k] = 0; cursor[k] = 0; }
        for (int k = i; k < N_GRAPHS * 96; k += stride) out_zero[k] = 0.0f;
        if (i < 128) agg[i] = -1;
    }
    if (i < 64 * P.DIN) {
        int j = i / P.DIN, k = i % P.DIN;
        P.w1T[i] = P.w1[k * 64 + j];
    }
    int i2 = i - 64 * P.DIN;
    if (i2 >= 0 && i2 < P.DOUT * 64) {
        int c = i2 / 64, j = i2 % 64;
        float s = P.g[c] * rsqrtf(P.v[c] + BN_EPS);
        P.w2sT[i2] = P.w2[j * P.DOUT + c] * s;
    }
    int i3 = i2 - P.DOUT * 64;
    if (i3 >= 0 && i3 < P.DOUT) {
        float s = P.g[i3] * rsqrtf(P.v[i3] + BN_EPS);
        P.bias2[i3] = (P.b2[i3] - P.m[i3]) * s + P.bb[i3];
    }
}

// ===========================================================================
// FUSED gather + mid layer (R13-proven: 512 threads, 2 rows/thread GEMMs).
// ===========================================================================
__global__ __launch_bounds__(512)
void fused_gather_mid_kernel(const bf16_t* __restrict__ y,
                             const int* __restrict__ rowptr,
                             const int* __restrict__ eids,
                             const float* __restrict__ b1,
                             const float* __restrict__ w2sT,
                             const float* __restrict__ bias2,
                             const float* __restrict__ w1nT,
                             bf16_t* __restrict__ ynext, int n_nodes) {
    constexpr int SS = 68;
    __shared__ float sT[64 * SS];
    __shared__ float wbuf[64 * 64];
    const int tid = threadIdx.x;
    const long base = (long)blockIdx.x * 64;

    const float4* gw2 = (const float4*)w2sT;
    for (int i4 = tid; i4 < 16 * 64; i4 += 512) {
        int row = i4 >> 4, k4 = i4 & 15;
        *(float4*)&wbuf[row * 64 + ((k4 ^ ((row >> 2) & 7)) << 2)] = gw2[i4];
    }
    // gather phase (the expensive, latency-bound part)
    gather_tile_to_lds512<SS>(y, rowptr, eids, b1, sT, base, n_nodes, tid);
    __syncthreads();

    const int jg = tid & 15, ng = tid >> 4, xw = jg & 7;  // ng 0..31, 2 rows each

    float h[2][4];
    {
        const float* wp = &wbuf[(jg * 4) * 64];
        float acc[2][4] = {};
        #pragma unroll 4
        for (int k4 = 0; k4 < 16; ++k4) {
            const int ko = (k4 ^ xw) << 2;
            float4 w0 = *(const float4*)&wp[0 * 64 + ko];
            float4 w1v = *(const float4*)&wp[1 * 64 + ko];
            float4 w2v = *(const float4*)&wp[2 * 64 + ko];
            float4 w3v = *(const float4*)&wp[3 * 64 + ko];
            #pragma unroll
            for (int i = 0; i < 2; ++i) {
                float4 a = *(const float4*)&sT[(ng * 2 + i) * SS + k4 * 4];
                acc[i][0] = fmaf(a.x, w0.x, fmaf(a.y, w0.y, fmaf(a.z, w0.z, fmaf(a.w, w0.w, acc[i][0]))));
                acc[i][1] = fmaf(a.x, w1v.x, fmaf(a.y, w1v.y, fmaf(a.z, w1v.z, fmaf(a.w, w1v.w, acc[i][1]))));
                acc[i][2] = fmaf(a.x, w2v.x, fmaf(a.y, w2v.y, fmaf(a.z, w2v.z, fmaf(a.w, w2v.w, acc[i][2]))));
                acc[i][3] = fmaf(a.x, w3v.x, fmaf(a.y, w3v.y, fmaf(a.z, w3v.z, fmaf(a.w, w3v.w, acc[i][3]))));
            }
        }
        float4 bv = *(const float4*)&bias2[jg * 4];
        #pragma unroll
        for (int i = 0; i < 2; ++i) {
            h[i][0] = fmaxf(acc[i][0] + bv.x, 0.0f);
            h[i][1] = fmaxf(acc[i][1] + bv.y, 0.0f);
            h[i][2] = fmaxf(acc[i][2] + bv.z, 0.0f);
            h[i][3] = fmaxf(acc[i][3] + bv.w, 0.0f);
        }
    }
    __syncthreads();

    #pragma unroll
    for (int i = 0; i < 2; ++i) {
        float4 hv = {h[i][0], h[i][1], h[i][2], h[i][3]};
        *(float4*)&sT[(ng * 2 + i) * SS + jg * 4] = hv;
    }
    const float4* gw1n = (const float4*)w1nT;
    for (int i4 = tid; i4 < 16 * 64; i4 += 512) {
        int row = i4 >> 4, k4 = i4 & 15;
        *(float4*)&wbuf[row * 64 + ((k4 ^ ((row >> 2) & 7)) << 2)] = gw1n[i4];
    }
    __syncthreads();

    {
        const float* ap = &sT[(ng * 2) * SS];
        const float* wp = &wbuf[(jg * 4) * 64];
        float acc[2][4] = {};
        #pragma unroll 4
        for (int k4 = 0; k4 < 16; ++k4) {
            const int ko = (k4 ^ xw) << 2;
            float4 w0 = *(const float4*)&wp[0 * 64 + ko];
            float4 w1v = *(const float4*)&wp[1 * 64 + ko];
            float4 w2v = *(const float4*)&wp[2 * 64 + ko];
            float4 w3v = *(const float4*)&wp[3 * 64 + ko];
            #pragma unroll
            for (int i = 0; i < 2; ++i) {
                float4 a = *(const float4*)&ap[i * SS + k4 * 4];
                acc[i][0] = fmaf(a.x, w0.x, fmaf(a.y, w0.y, fmaf(a.z, w0.z, fmaf(a.w, w0.w, acc[i][0]))));
                acc[i][1] = fmaf(a.x, w1v.x, fmaf(a.y, w1v.y, fmaf(a.z, w1v.z, fmaf(a.w, w1v.w, acc[i][1]))));
                acc[i][2] = fmaf(a.x, w2v.x, fmaf(a.y, w2v.y, fmaf(a.z, w2v.z, fmaf(a.w, w2v.w, acc[i][2]))));
                acc[i][3] = fmaf(a.x, w3v.x, fmaf(a.y, w3v.y, fmaf(a.z, w3v.z, fmaf(a.w, w3v.w, acc[i][3]))));
            }
        }
        #pragma unroll
        for (int i = 0; i < 2; ++i) {
            long n = base + ng * 2 + i;
            if (n < n_nodes) {
                *(uint2*)(ynext + n * 64 + jg * 4) = pack4(acc[i][0], acc[i][1], acc[i][2], acc[i][3]);
            }
        }
    }
}

// ===========================================================================
// FUSED gather + final layer + mean-pool (R13-proven: 512 threads).
// ===========================================================================
__global__ __launch_bounds__(512)
void fused_gather_final_kernel(const bf16_t* __restrict__ y,
                               const int* __restrict__ rowptr,
                               const int* __restrict__ eids,
                               const float* __restrict__ b1,
                               const float* __restrict__ w2sT,
                               const float* __restrict__ bias2,
                               const int* __restrict__ batch,
                               const int* __restrict__ gstart,
                               float* __restrict__ out, int n_nodes) {
    constexpr int CPT = 6;
    constexpr int SS = 68;
    __shared__ float w2s[96 * 64];  // later reused as hbuf[64][96]
    __shared__ float tbuf[64 * SS];
    const int tid = threadIdx.x;
    const long base = (long)blockIdx.x * 64;

    const float4* gw2 = (const float4*)w2sT;
    for (int i4 = tid; i4 < 96 * 16; i4 += 512) {
        int row = i4 >> 4, k4 = i4 & 15;
        *(float4*)&w2s[row * 64 + ((k4 ^ ((row / CPT) & 7)) << 2)] = gw2[i4];
    }
    // gather phase
    gather_tile_to_lds512<SS>(y, rowptr, eids, b1, tbuf, base, n_nodes, tid);
    __syncthreads();

    const int cg_ = tid & 15, ng = tid >> 4, xw = cg_ & 7;  // ng 0..31
    const float* wp = &w2s[(cg_ * CPT) * 64];
    float acc[2][CPT] = {};
    #pragma unroll 4
    for (int k4 = 0; k4 < 16; ++k4) {
        const int ko = (k4 ^ xw) << 2;
        float4 wv[CPT];
        #pragma unroll
        for (int c = 0; c < CPT; ++c) wv[c] = *(const float4*)&wp[c * 64 + ko];
        #pragma unroll
        for (int i = 0; i < 2; ++i) {
            float4 h = *(const float4*)&tbuf[(ng * 2 + i) * SS + k4 * 4];
            #pragma unroll
            for (int c = 0; c < CPT; ++c)
                acc[i][c] = fmaf(h.x, wv[c].x, fmaf(h.y, wv[c].y, fmaf(h.z, wv[c].z, fmaf(h.w, wv[c].w, acc[i][c]))));
        }
    }
    float bv[CPT];
    #pragma unroll
    for (int c = 0; c < CPT; ++c) bv[c] = bias2[cg_ * CPT + c];
    __syncthreads();  // all w2s weight reads done; buffer becomes hbuf
    #pragma unroll
    for (int i = 0; i < 2; ++i) {
        long n = base + ng * 2 + i;
        float* hp = &w2s[(ng * 2 + i) * 96 + cg_ * CPT];
        if (n < n_nodes) {
            #pragma unroll
            for (int c = 0; c < CPT; ++c) hp[c] = fmaxf(acc[i][c] + bv[c], 0.0f);
        } else {
            #pragma unroll
            for (int c = 0; c < CPT; ++c) hp[c] = 0.0f;
        }
    }
    __syncthreads();

    // per-graph column sums over this block's 64 sorted rows
    if (tid < 96) {
        int limit = (int)((n_nodes - base < 64) ? (n_nodes - base) : 64);
        int gcur = batch[base];
        float s = 0.0f;
        for (int r = 0; r < limit; ++r) {
            int g = batch[base + r];
            if (g != gcur) {
                float inv = 1.0f / fmaxf((float)(gstart[gcur + 1] - gstart[gcur]), 1.0f);
                atomicAdd(&out[gcur * 96 + tid], s * inv);
                s = 0.0f;
                gcur = g;
            }
            s += w2s[r * 96 + tid];
        }
        float inv = 1.0f / fmaxf((float)(gstart[gcur + 1] - gstart[gcur]), 1.0f);
        atomicAdd(&out[gcur * 96 + tid], s * inv);
    }
}

// ---------------------------------------------------------------------------
static inline int cdiv_l(long a, int b) { return (int)((a + b - 1) / b); }

extern "C" void kernel_launch(void* const* d_in, const int* in_sizes, int n_in,
                              void* d_out, int out_size, void* d_ws, size_t ws_size,
                              hipStream_t stream) {
    const float* x     = (const float*)d_in[0];
    const int*   ei    = (const int*)d_in[1];
    const int*   src   = ei;
    const int*   dst   = ei + N_EDGES;
    const int*   batch = (const int*)d_in[2];

    const float* P[3][8];
    int p = 3;
    for (int l = 0; l < 3; ++l)
        for (int q = 0; q < 8; ++q)
            P[l][q] = (const float*)d_in[p++];

    const long NP = N_NODES + 128;
    char* wsb   = (char*)d_ws;
    bf16_t* yA  = (bf16_t*)wsb;                       // NP*64 bf16 (ping)
    bf16_t* yB  = yA + NP * 64;                       // NP*64 bf16 (pong)
    float* q    = (float*)(yB + NP * 64);
    float* w1T[3], *w2sT[3], *bias2[3];
    for (int l = 0; l < 3; ++l) {
        w1T[l] = q;   q += 64 * 128;
        w2sT[l] = q;  q += 96 * 64;
        bias2[l] = q; q += 96;
    }
    int* gstart   = (int*)q;
    int* deg      = gstart + 72;
    int* cursor   = deg + N_NODES;
    int* partials = cursor + N_NODES;   // scan aggregates (init -1)
    int* rowptr   = partials + 128;
    int* eids     = rowptr + (N_NODES + 1);

    const int B = 256;
    const int DIN[3]  = {128, 64, 64};
    const int DOUT[3] = {64, 64, 96};

    // ---- prep (zero deg/cursor/d_out, init scan slots, fold weights) ----
    PrepAll pa;
    for (int l = 0; l < 3; ++l) {
        pa.l[l].w1 = P[l][0]; pa.l[l].w2 = P[l][2]; pa.l[l].b2 = P[l][3];
        pa.l[l].g = P[l][4];  pa.l[l].bb = P[l][5]; pa.l[l].m = P[l][6];
        pa.l[l].v = P[l][7];
        pa.l[l].w1T = w1T[l]; pa.l[l].w2sT = w2sT[l]; pa.l[l].bias2 = bias2[l];
        pa.l[l].DIN = DIN[l]; pa.l[l].DOUT = DOUT[l];
    }
    dim3 pgrid(cdiv_l(64 * 128 + 96 * 64 + 96, B), 3);
    prep_all_kernel<<<pgrid, B, 0, stream>>>(pa, deg, cursor, (float*)d_out, partials);

    // ---- CSR histogram + scan ----
    deg_hist_kernel<<<cdiv_l(N_EDGES, B), B, 0, stream>>>(dst, deg, N_EDGES);
    int nblk = cdiv_l(N_NODES + 1, 1024);  // 98 blocks, all co-resident
    scan_fused_kernel<<<nblk, 1024, 0, stream>>>(deg, rowptr, partials, N_NODES, N_EDGES);

    // ---- merged CSR-fill (XCD-binned, placement-aligned) + layer-0 pre-GEMM --
    const int nfill  = cdiv_l(N_EDGES, B);        // 2344
    const int ngemm  = cdiv_l(N_NODES, 64);       // 1563
    const int ngrp_f = cdiv_l(nfill, 3);          // 782
    const int ngrp_g = cdiv_l(ngemm, 2);          // 782
    const int ngroups = (ngrp_f > ngrp_g) ? ngrp_f : ngrp_g;
    fill_pre_kernel<<<ngroups * 5, B, 0, stream>>>(
        src, dst, rowptr, cursor, eids, batch, gstart,
        x, w1T[0], yA, N_EDGES, N_NODES);

    const int ntiles = cdiv_l(N_NODES, 64);

    // ---- layer 0 (gather fused into MLP) ----
    fused_gather_mid_kernel<<<ntiles, 512, 0, stream>>>(
        yA, rowptr, eids, P[0][1], w2sT[0], bias2[0], w1T[1], yB, N_NODES);
    // ---- layer 1 ----
    fused_gather_mid_kernel<<<ntiles, 512, 0, stream>>>(
        yB, rowptr, eids, P[1][1], w2sT[1], bias2[1], w1T[2], yA, N_NODES);
    // ---- layer 2 (+ pool fused) ----
    fused_gather_final_kernel<<<ntiles, 512, 0, stream>>>(
        yA, rowptr, eids, P[2][1], w2sT[2], bias2[2], batch, gstart,
        (float*)d_out, N_NODES);
}

// Round 12
// 353.631 us; speedup vs baseline: 1.0079x; 1.0079x over previous
//
#include <hip/hip_runtime.h>

#define N_NODES 100000
#define N_GRAPHS 64
#define N_EDGES 600000
#define BN_EPS 1e-5f

typedef unsigned short bf16_t;

__device__ __forceinline__ unsigned short f2bf(float f) {
    unsigned int u = __float_as_uint(f);
    u += 0x7FFF + ((u >> 16) & 1);
    return (unsigned short)(u >> 16);
}
__device__ __forceinline__ uint2 pack4(float a, float b, float c, float d) {
    uint2 p;
    p.x = (unsigned)f2bf(a) | ((unsigned)f2bf(b) << 16);
    p.y = (unsigned)f2bf(c) | ((unsigned)f2bf(d) << 16);
    return p;
}
// accumulate 8 bf16 (uint4) into acc[0..7]
__device__ __forceinline__ void bf8_acc(uint4 q, float* acc) {
    acc[0] += __uint_as_float(q.x << 16);
    acc[1] += __uint_as_float(q.x & 0xFFFF0000u);
    acc[2] += __uint_as_float(q.y << 16);
    acc[3] += __uint_as_float(q.y & 0xFFFF0000u);
    acc[4] += __uint_as_float(q.z << 16);
    acc[5] += __uint_as_float(q.z & 0xFFFF0000u);
    acc[6] += __uint_as_float(q.w << 16);
    acc[7] += __uint_as_float(q.w & 0xFFFF0000u);
}

// Gather one 64-node tile into LDS (stride SS), bias+ReLU applied.
// R3-proven form: 512-thread single pass, 8 lanes/node, unroll-4 + tail.
template <int SS>
__device__ __forceinline__ void gather_tile_to_lds512(
    const bf16_t* __restrict__ y, const int* __restrict__ rowptr,
    const int* __restrict__ eids, const float* __restrict__ b1,
    float* sT, long base, int n_nodes, int tid) {
    const uint4* yv = (const uint4*)y;
    const int f = tid & 7;
    const int lr = tid >> 3;   // local row 0..63
    float4 b0 = ((const float4*)b1)[f * 2];
    float4 b1v = ((const float4*)b1)[f * 2 + 1];
    long node = base + lr;
    float* sp = &sT[lr * SS + f * 8];
    if (node < n_nodes) {
        float acc[8] = {};
        bf8_acc(yv[node * 8 + f], acc);
        int bgn = rowptr[node], end = rowptr[node + 1];
        int i = bgn;
        for (; i + 3 < end; i += 4) {
            int s0 = eids[i], s1 = eids[i + 1], s2 = eids[i + 2], s3 = eids[i + 3];
            uint4 q0 = yv[(long)s0 * 8 + f];
            uint4 q1 = yv[(long)s1 * 8 + f];
            uint4 q2 = yv[(long)s2 * 8 + f];
            uint4 q3 = yv[(long)s3 * 8 + f];
            bf8_acc(q0, acc); bf8_acc(q1, acc); bf8_acc(q2, acc); bf8_acc(q3, acc);
        }
        for (; i < end; ++i) bf8_acc(yv[(long)eids[i] * 8 + f], acc);
        float4 o0, o1;
        o0.x = fmaxf(acc[0] + b0.x, 0.0f);
        o0.y = fmaxf(acc[1] + b0.y, 0.0f);
        o0.z = fmaxf(acc[2] + b0.z, 0.0f);
        o0.w = fmaxf(acc[3] + b0.w, 0.0f);
        o1.x = fmaxf(acc[4] + b1v.x, 0.0f);
        o1.y = fmaxf(acc[5] + b1v.y, 0.0f);
        o1.z = fmaxf(acc[6] + b1v.z, 0.0f);
        o1.w = fmaxf(acc[7] + b1v.w, 0.0f);
        *(float4*)sp = o0;
        *(float4*)(sp + 4) = o1;
    } else {
        float4 z = {0.0f, 0.0f, 0.0f, 0.0f};
        *(float4*)sp = z;
        *(float4*)(sp + 4) = z;
    }
}

// ===========================================================================
// CSR build
// ===========================================================================
__global__ void deg_hist_kernel(const int* __restrict__ dst,
                                int* __restrict__ deg, int n_edges) {
    int e = blockIdx.x * blockDim.x + threadIdx.x;
    if (e < n_edges) atomicAdd(&deg[dst[e]], 1);
}

// One-kernel exclusive scan: per-block scan + aggregate publish (atomicExch
// into -1-initialized slot) + parallel spin-read of predecessors (atomicAdd,
// device-scope => cross-XCD safe). All 98 blocks co-resident.
// R20: ALSO writes cursor[i] = rowptr[i] so the fill can atomicAdd cursor
// directly (no rowptr load in its dependency chain).
__global__ __launch_bounds__(1024)
void scan_fused_kernel(const int* __restrict__ deg, int* __restrict__ rowptr,
                       int* __restrict__ cursor, int* __restrict__ agg,
                       int n, int total) {
    __shared__ int s[1024];
    __shared__ int s2[128];
    __shared__ int offset_sh;
    const int b = blockIdx.x;
    const int i = b * 1024 + threadIdx.x;
    int v = (i < n) ? deg[i] : 0;
    s[threadIdx.x] = v;
    __syncthreads();
    for (int off = 1; off < 1024; off <<= 1) {
        int t = (threadIdx.x >= (unsigned)off) ? s[threadIdx.x - off] : 0;
        __syncthreads();
        s[threadIdx.x] += t;
        __syncthreads();
    }
    // publish this block's total (slot pre-initialized to -1 by prep)
    if (threadIdx.x == 1023) atomicExch(&agg[b], s[1023]);
    // threads 0..b-1 spin-read predecessor aggregates
    if (threadIdx.x < b) {
        int val;
        do { val = atomicAdd(&agg[threadIdx.x], 0); } while (val == -1);
        s2[threadIdx.x] = val;
    }
    __syncthreads();
    if (threadIdx.x == 0) {
        int off = 0;
        for (int k = 0; k < b; ++k) off += s2[k];
        offset_sh = off;
    }
    __syncthreads();
    const int off = offset_sh;
    if (i < n) {
        int rp = off + s[threadIdx.x] - v;
        rowptr[i] = rp;
        cursor[i] = rp;    // fill scatters via atomicAdd(cursor) alone
    } else if (i == n) {
        rowptr[n] = total;
    }
}

// ===========================================================================
// MERGED fill_bounds + pre_gemm (R11-proven config: 256 threads, 3:2).
// R20: fill role drops the rowptr load — cursor pre-initialized to rowptr by
// the scan, so pos = atomicAdd(&cursor[t],1) directly. Dependent random-
// access chain per edge: 2 ops -> 1 op before the scatter store.
// ===========================================================================
__global__ __launch_bounds__(256)
void fill_pre_kernel(const int* __restrict__ src, const int* __restrict__ dst,
                     int* __restrict__ cursor,
                     int* __restrict__ eids, const int* __restrict__ batch,
                     int* __restrict__ gstart,
                     const float* __restrict__ x, const float* __restrict__ w1T,
                     bf16_t* __restrict__ y, int n_edges, int n_nodes) {
    __shared__ float w1s[64 * 128];
    const int bq = blockIdx.x / 5, br = blockIdx.x % 5;

    if (br < 3) {
        // ------------------- fill role (3 of every 5 blocks) -------------------
        int e = (bq * 3 + br) * 256 + threadIdx.x;
        if (e < n_edges) {
            int t = dst[e];
            int pos = atomicAdd(&cursor[t], 1);
            eids[pos] = src[e];
        }
        if (e < n_nodes) {
            if (e == 0) {
                for (int g = 0; g <= batch[0]; ++g) gstart[g] = 0;
            } else {
                int b0 = batch[e - 1], b1 = batch[e];
                for (int g = b0 + 1; g <= b1; ++g) gstart[g] = e;
            }
            if (e == n_nodes - 1) {
                for (int g = batch[e] + 1; g <= N_GRAPHS; ++g) gstart[g] = n_nodes;
            }
        }
        return;
    }

    // ------------------- gemm role (2 of every 5 blocks) -------------------
    const int gb = bq * 2 + (br - 3);
    const long base = (long)gb * 64;
    if (base >= n_nodes) return;
    const int tid = threadIdx.x;

    const float4* gw1 = (const float4*)w1T;
    for (int i4 = tid; i4 < 16 * 128; i4 += 256) {
        int row = i4 >> 5, k4 = i4 & 31;
        *(float4*)&w1s[row * 128 + ((k4 ^ ((row >> 2) & 7)) << 2)] = gw1[i4];
    }
    __syncthreads();

    const int jg = tid & 15, ng = tid >> 4, xw = jg & 7;
    const float* wp = &w1s[(jg * 4) * 128];
    const float4* xv = (const float4*)x;
    long r[4];
    #pragma unroll
    for (int i = 0; i < 4; ++i) {
        long rr = base + ng * 4 + i;
        r[i] = (rr < n_nodes) ? rr : (n_nodes - 1);  // clamp: x has no padding
    }
    float acc[4][4] = {};
    #pragma unroll 4
    for (int k4 = 0; k4 < 32; ++k4) {
        const int ko = (k4 ^ xw) << 2;
        float4 w0 = *(const float4*)&wp[0 * 128 + ko];
        float4 w1v = *(const float4*)&wp[1 * 128 + ko];
        float4 w2v = *(const float4*)&wp[2 * 128 + ko];
        float4 w3v = *(const float4*)&wp[3 * 128 + ko];
        #pragma unroll
        for (int i = 0; i < 4; ++i) {
            float4 a = xv[r[i] * 32 + k4];
            acc[i][0] = fmaf(a.x, w0.x, fmaf(a.y, w0.y, fmaf(a.z, w0.z, fmaf(a.w, w0.w, acc[i][0]))));
            acc[i][1] = fmaf(a.x, w1v.x, fmaf(a.y, w1v.y, fmaf(a.z, w1v.z, fmaf(a.w, w1v.w, acc[i][1]))));
            acc[i][2] = fmaf(a.x, w2v.x, fmaf(a.y, w2v.y, fmaf(a.z, w2v.z, fmaf(a.w, w2v.w, acc[i][2]))));
            acc[i][3] = fmaf(a.x, w3v.x, fmaf(a.y, w3v.y, fmaf(a.z, w3v.z, fmaf(a.w, w3v.w, acc[i][3]))));
        }
    }
    #pragma unroll
    for (int i = 0; i < 4; ++i) {
        long n = base + ng * 4 + i;
        if (n < n_nodes) {
            *(uint2*)(y + n * 64 + jg * 4) = pack4(acc[i][0], acc[i][1], acc[i][2], acc[i][3]);
        }
    }
}

// ===========================================================================
// Prep (blockIdx.y = layer); y==0 blocks also zero deg/d_out and init scan
// aggregates to -1. (cursor is fully overwritten by the scan; no zeroing.)
// ===========================================================================
struct LayerPrep {
    const float *w1, *w2, *b2, *g, *bb, *m, *v;
    float *w1T, *w2sT, *bias2;
    int DIN, DOUT;
};
struct PrepAll { LayerPrep l[3]; };

__global__ void prep_all_kernel(PrepAll pa, int* __restrict__ deg,
                                float* __restrict__ out_zero,
                                int* __restrict__ agg) {
    LayerPrep P = pa.l[blockIdx.y];
    int i = blockIdx.x * blockDim.x + threadIdx.x;
    if (blockIdx.y == 0) {
        int stride = gridDim.x * blockDim.x;
        for (int k = i; k < N_NODES; k += stride) deg[k] = 0;
        for (int k = i; k < N_GRAPHS * 96; k += stride) out_zero[k] = 0.0f;
        if (i < 128) agg[i] = -1;
    }
    if (i < 64 * P.DIN) {
        int j = i / P.DIN, k = i % P.DIN;
        P.w1T[i] = P.w1[k * 64 + j];
    }
    int i2 = i - 64 * P.DIN;
    if (i2 >= 0 && i2 < P.DOUT * 64) {
        int c = i2 / 64, j = i2 % 64;
        float s = P.g[c] * rsqrtf(P.v[c] + BN_EPS);
        P.w2sT[i2] = P.w2[j * P.DOUT + c] * s;
    }
    int i3 = i2 - P.DOUT * 64;
    if (i3 >= 0 && i3 < P.DOUT) {
        float s = P.g[i3] * rsqrtf(P.v[i3] + BN_EPS);
        P.bias2[i3] = (P.b2[i3] - P.m[i3]) * s + P.bb[i3];
    }
}

// ===========================================================================
// FUSED gather + mid layer (R13-proven: 512 threads, 2 rows/thread GEMMs).
// ===========================================================================
__global__ __launch_bounds__(512)
void fused_gather_mid_kernel(const bf16_t* __restrict__ y,
                             const int* __restrict__ rowptr,
                             const int* __restrict__ eids,
                             const float* __restrict__ b1,
                             const float* __restrict__ w2sT,
                             const float* __restrict__ bias2,
                             const float* __restrict__ w1nT,
                             bf16_t* __restrict__ ynext, int n_nodes) {
    constexpr int SS = 68;
    __shared__ float sT[64 * SS];
    __shared__ float wbuf[64 * 64];
    const int tid = threadIdx.x;
    const long base = (long)blockIdx.x * 64;

    const float4* gw2 = (const float4*)w2sT;
    for (int i4 = tid; i4 < 16 * 64; i4 += 512) {
        int row = i4 >> 4, k4 = i4 & 15;
        *(float4*)&wbuf[row * 64 + ((k4 ^ ((row >> 2) & 7)) << 2)] = gw2[i4];
    }
    // gather phase (the expensive, latency-bound part)
    gather_tile_to_lds512<SS>(y, rowptr, eids, b1, sT, base, n_nodes, tid);
    __syncthreads();

    const int jg = tid & 15, ng = tid >> 4, xw = jg & 7;  // ng 0..31, 2 rows each

    float h[2][4];
    {
        const float* wp = &wbuf[(jg * 4) * 64];
        float acc[2][4] = {};
        #pragma unroll 4
        for (int k4 = 0; k4 < 16; ++k4) {
            const int ko = (k4 ^ xw) << 2;
            float4 w0 = *(const float4*)&wp[0 * 64 + ko];
            float4 w1v = *(const float4*)&wp[1 * 64 + ko];
            float4 w2v = *(const float4*)&wp[2 * 64 + ko];
            float4 w3v = *(const float4*)&wp[3 * 64 + ko];
            #pragma unroll
            for (int i = 0; i < 2; ++i) {
                float4 a = *(const float4*)&sT[(ng * 2 + i) * SS + k4 * 4];
                acc[i][0] = fmaf(a.x, w0.x, fmaf(a.y, w0.y, fmaf(a.z, w0.z, fmaf(a.w, w0.w, acc[i][0]))));
                acc[i][1] = fmaf(a.x, w1v.x, fmaf(a.y, w1v.y, fmaf(a.z, w1v.z, fmaf(a.w, w1v.w, acc[i][1]))));
                acc[i][2] = fmaf(a.x, w2v.x, fmaf(a.y, w2v.y, fmaf(a.z, w2v.z, fmaf(a.w, w2v.w, acc[i][2]))));
                acc[i][3] = fmaf(a.x, w3v.x, fmaf(a.y, w3v.y, fmaf(a.z, w3v.z, fmaf(a.w, w3v.w, acc[i][3]))));
            }
        }
        float4 bv = *(const float4*)&bias2[jg * 4];
        #pragma unroll
        for (int i = 0; i < 2; ++i) {
            h[i][0] = fmaxf(acc[i][0] + bv.x, 0.0f);
            h[i][1] = fmaxf(acc[i][1] + bv.y, 0.0f);
            h[i][2] = fmaxf(acc[i][2] + bv.z, 0.0f);
            h[i][3] = fmaxf(acc[i][3] + bv.w, 0.0f);
        }
    }
    __syncthreads();

    #pragma unroll
    for (int i = 0; i < 2; ++i) {
        float4 hv = {h[i][0], h[i][1], h[i][2], h[i][3]};
        *(float4*)&sT[(ng * 2 + i) * SS + jg * 4] = hv;
    }
    const float4* gw1n = (const float4*)w1nT;
    for (int i4 = tid; i4 < 16 * 64; i4 += 512) {
        int row = i4 >> 4, k4 = i4 & 15;
        *(float4*)&wbuf[row * 64 + ((k4 ^ ((row >> 2) & 7)) << 2)] = gw1n[i4];
    }
    __syncthreads();

    {
        const float* ap = &sT[(ng * 2) * SS];
        const float* wp = &wbuf[(jg * 4) * 64];
        float acc[2][4] = {};
        #pragma unroll 4
        for (int k4 = 0; k4 < 16; ++k4) {
            const int ko = (k4 ^ xw) << 2;
            float4 w0 = *(const float4*)&wp[0 * 64 + ko];
            float4 w1v = *(const float4*)&wp[1 * 64 + ko];
            float4 w2v = *(const float4*)&wp[2 * 64 + ko];
            float4 w3v = *(const float4*)&wp[3 * 64 + ko];
            #pragma unroll
            for (int i = 0; i < 2; ++i) {
                float4 a = *(const float4*)&ap[i * SS + k4 * 4];
                acc[i][0] = fmaf(a.x, w0.x, fmaf(a.y, w0.y, fmaf(a.z, w0.z, fmaf(a.w, w0.w, acc[i][0]))));
                acc[i][1] = fmaf(a.x, w1v.x, fmaf(a.y, w1v.y, fmaf(a.z, w1v.z, fmaf(a.w, w1v.w, acc[i][1]))));
                acc[i][2] = fmaf(a.x, w2v.x, fmaf(a.y, w2v.y, fmaf(a.z, w2v.z, fmaf(a.w, w2v.w, acc[i][2]))));
                acc[i][3] = fmaf(a.x, w3v.x, fmaf(a.y, w3v.y, fmaf(a.z, w3v.z, fmaf(a.w, w3v.w, acc[i][3]))));
            }
        }
        #pragma unroll
        for (int i = 0; i < 2; ++i) {
            long n = base + ng * 2 + i;
            if (n < n_nodes) {
                *(uint2*)(ynext + n * 64 + jg * 4) = pack4(acc[i][0], acc[i][1], acc[i][2], acc[i][3]);
            }
        }
    }
}

// ===========================================================================
// FUSED gather + final layer + mean-pool (R13-proven: 512 threads).
// ===========================================================================
__global__ __launch_bounds__(512)
void fused_gather_final_kernel(const bf16_t* __restrict__ y,
                               const int* __restrict__ rowptr,
                               const int* __restrict__ eids,
                               const float* __restrict__ b1,
                               const float* __restrict__ w2sT,
                               const float* __restrict__ bias2,
                               const int* __restrict__ batch,
                               const int* __restrict__ gstart,
                               float* __restrict__ out, int n_nodes) {
    constexpr int CPT = 6;
    constexpr int SS = 68;
    __shared__ float w2s[96 * 64];  // later reused as hbuf[64][96]
    __shared__ float tbuf[64 * SS];
    const int tid = threadIdx.x;
    const long base = (long)blockIdx.x * 64;

    const float4* gw2 = (const float4*)w2sT;
    for (int i4 = tid; i4 < 96 * 16; i4 += 512) {
        int row = i4 >> 4, k4 = i4 & 15;
        *(float4*)&w2s[row * 64 + ((k4 ^ ((row / CPT) & 7)) << 2)] = gw2[i4];
    }
    // gather phase
    gather_tile_to_lds512<SS>(y, rowptr, eids, b1, tbuf, base, n_nodes, tid);
    __syncthreads();

    const int cg_ = tid & 15, ng = tid >> 4, xw = cg_ & 7;  // ng 0..31
    const float* wp = &w2s[(cg_ * CPT) * 64];
    float acc[2][CPT] = {};
    #pragma unroll 4
    for (int k4 = 0; k4 < 16; ++k4) {
        const int ko = (k4 ^ xw) << 2;
        float4 wv[CPT];
        #pragma unroll
        for (int c = 0; c < CPT; ++c) wv[c] = *(const float4*)&wp[c * 64 + ko];
        #pragma unroll
        for (int i = 0; i < 2; ++i) {
            float4 h = *(const float4*)&tbuf[(ng * 2 + i) * SS + k4 * 4];
            #pragma unroll
            for (int c = 0; c < CPT; ++c)
                acc[i][c] = fmaf(h.x, wv[c].x, fmaf(h.y, wv[c].y, fmaf(h.z, wv[c].z, fmaf(h.w, wv[c].w, acc[i][c]))));
        }
    }
    float bv[CPT];
    #pragma unroll
    for (int c = 0; c < CPT; ++c) bv[c] = bias2[cg_ * CPT + c];
    __syncthreads();  // all w2s weight reads done; buffer becomes hbuf
    #pragma unroll
    for (int i = 0; i < 2; ++i) {
        long n = base + ng * 2 + i;
        float* hp = &w2s[(ng * 2 + i) * 96 + cg_ * CPT];
        if (n < n_nodes) {
            #pragma unroll
            for (int c = 0; c < CPT; ++c) hp[c] = fmaxf(acc[i][c] + bv[c], 0.0f);
        } else {
            #pragma unroll
            for (int c = 0; c < CPT; ++c) hp[c] = 0.0f;
        }
    }
    __syncthreads();

    // per-graph column sums over this block's 64 sorted rows
    if (tid < 96) {
        int limit = (int)((n_nodes - base < 64) ? (n_nodes - base) : 64);
        int gcur = batch[base];
        float s = 0.0f;
        for (int r = 0; r < limit; ++r) {
            int g = batch[base + r];
            if (g != gcur) {
                float inv = 1.0f / fmaxf((float)(gstart[gcur + 1] - gstart[gcur]), 1.0f);
                atomicAdd(&out[gcur * 96 + tid], s * inv);
                s = 0.0f;
                gcur = g;
            }
            s += w2s[r * 96 + tid];
        }
        float inv = 1.0f / fmaxf((float)(gstart[gcur + 1] - gstart[gcur]), 1.0f);
        atomicAdd(&out[gcur * 96 + tid], s * inv);
    }
}

// ---------------------------------------------------------------------------
static inline int cdiv_l(long a, int b) { return (int)((a + b - 1) / b); }

extern "C" void kernel_launch(void* const* d_in, const int* in_sizes, int n_in,
                              void* d_out, int out_size, void* d_ws, size_t ws_size,
                              hipStream_t stream) {
    const float* x     = (const float*)d_in[0];
    const int*   ei    = (const int*)d_in[1];
    const int*   src   = ei;
    const int*   dst   = ei + N_EDGES;
    const int*   batch = (const int*)d_in[2];

    const float* P[3][8];
    int p = 3;
    for (int l = 0; l < 3; ++l)
        for (int q = 0; q < 8; ++q)
            P[l][q] = (const float*)d_in[p++];

    const long NP = N_NODES + 128;
    char* wsb   = (char*)d_ws;
    bf16_t* yA  = (bf16_t*)wsb;                       // NP*64 bf16 (ping)
    bf16_t* yB  = yA + NP * 64;                       // NP*64 bf16 (pong)
    float* q    = (float*)(yB + NP * 64);
    float* w1T[3], *w2sT[3], *bias2[3];
    for (int l = 0; l < 3; ++l) {
        w1T[l] = q;   q += 64 * 128;
        w2sT[l] = q;  q += 96 * 64;
        bias2[l] = q; q += 96;
    }
    int* gstart   = (int*)q;
    int* deg      = gstart + 72;
    int* cursor   = deg + N_NODES;
    int* partials = cursor + N_NODES;   // scan aggregates (init -1)
    int* rowptr   = partials + 128;
    int* eids     = rowptr + (N_NODES + 1);

    const int B = 256;
    const int DIN[3]  = {128, 64, 64};
    const int DOUT[3] = {64, 64, 96};

    // ---- prep (zero deg/d_out, init scan slots, fold weights) ----
    PrepAll pa;
    for (int l = 0; l < 3; ++l) {
        pa.l[l].w1 = P[l][0]; pa.l[l].w2 = P[l][2]; pa.l[l].b2 = P[l][3];
        pa.l[l].g = P[l][4];  pa.l[l].bb = P[l][5]; pa.l[l].m = P[l][6];
        pa.l[l].v = P[l][7];
        pa.l[l].w1T = w1T[l]; pa.l[l].w2sT = w2sT[l]; pa.l[l].bias2 = bias2[l];
        pa.l[l].DIN = DIN[l]; pa.l[l].DOUT = DOUT[l];
    }
    dim3 pgrid(cdiv_l(64 * 128 + 96 * 64 + 96, B), 3);
    prep_all_kernel<<<pgrid, B, 0, stream>>>(pa, deg, (float*)d_out, partials);

    // ---- CSR histogram + scan (scan also seeds cursor=rowptr) ----
    deg_hist_kernel<<<cdiv_l(N_EDGES, B), B, 0, stream>>>(dst, deg, N_EDGES);
    int nblk = cdiv_l(N_NODES + 1, 1024);  // 98 blocks, all co-resident
    scan_fused_kernel<<<nblk, 1024, 0, stream>>>(deg, rowptr, cursor, partials,
                                                 N_NODES, N_EDGES);

    // ---- merged CSR-fill (cursor-direct) + layer-0 pre-GEMM ----
    const int nfill  = cdiv_l(N_EDGES, B);        // 2344
    const int ngemm  = cdiv_l(N_NODES, 64);       // 1563
    const int ngrp_f = cdiv_l(nfill, 3);          // 782
    const int ngrp_g = cdiv_l(ngemm, 2);          // 782
    const int ngroups = (ngrp_f > ngrp_g) ? ngrp_f : ngrp_g;
    fill_pre_kernel<<<ngroups * 5, B, 0, stream>>>(
        src, dst, cursor, eids, batch, gstart,
        x, w1T[0], yA, N_EDGES, N_NODES);

    const int ntiles = cdiv_l(N_NODES, 64);

    // ---- layer 0 (gather fused into MLP) ----
    fused_gather_mid_kernel<<<ntiles, 512, 0, stream>>>(
        yA, rowptr, eids, P[0][1], w2sT[0], bias2[0], w1T[1], yB, N_NODES);
    // ---- layer 1 ----
    fused_gather_mid_kernel<<<ntiles, 512, 0, stream>>>(
        yB, rowptr, eids, P[1][1], w2sT[1], bias2[1], w1T[2], yA, N_NODES);
    // ---- layer 2 (+ pool fused) ----
    fused_gather_final_kernel<<<ntiles, 512, 0, stream>>>(
        yA, rowptr, eids, P[2][1], w2sT[2], bias2[2], batch, gstart,
        (float*)d_out, N_NODES);
}